// Round 1
// baseline (28.428 us; speedup 1.0000x reference)
//
#include <hip/hip_runtime.h>
#include <math.h>

// SGO_Loss_Prod: B=16 structures, N=256 atoms, K=16 ops, r=0.4.
// Min-image collapse: r=0.4 < 0.5 so at most one of the 27 periodic shifts
// passes the mask per pair -> compute minimum image directly.

#define NATOMS 256
#define KOPS   16
#define NB     16
#define TASKS_PER_B (KOPS + 1)   // identity + 16 ops
#define JSPLIT 4
#define JCHUNK (NATOMS / JSPLIT)

// Replicates jnp.mod(x, 1.0): truncated remainder, then +1 if negative.
__device__ __forceinline__ float wrap01(float x) {
    float m = fmodf(x, 1.0f);
    if (m < 0.0f) m += 1.0f;
    return m;
}

__global__ __launch_bounds__(256) void pair_kernel(
    const float* __restrict__ fracs,
    const float* __restrict__ oprss,
    float* __restrict__ sums)        // [NB*17*JSPLIT][3]
{
    const int blk  = blockIdx.x;      // 0..1087
    const int task = blk >> 2;        // 0..271
    const int q    = blk & 3;         // j-chunk
    const int b    = task / TASKS_PER_B;
    const int t    = task % TASKS_PER_B;   // 0 = identity, 1..16 = op t-1

    const int i = threadIdx.x;        // src atom
    const float* f = fracs + (size_t)b * NATOMS * 3;

    __shared__ float sf[NATOMS][3];

    float fx = f[i*3+0], fy = f[i*3+1], fz = f[i*3+2];
    if (t > 0) {
        const float* op = oprss + (size_t)(b * KOPS + (t - 1)) * 9;
        // f1[i] = f[i] @ opr.T  -> component c = dot(opr row c, f[i]); then mod 1
        float gx = wrap01(fx*op[0] + fy*op[1] + fz*op[2]);
        float gy = wrap01(fx*op[3] + fy*op[4] + fz*op[5]);
        float gz = wrap01(fx*op[6] + fy*op[7] + fz*op[8]);
        fx = gx; fy = gy; fz = gz;
    }
    sf[i][0] = fx; sf[i][1] = fy; sf[i][2] = fz;
    __syncthreads();

    float a0 = 0.f, a1 = 0.f, a2 = 0.f;
    const int j0 = q * JCHUNK;
    #pragma unroll 4
    for (int j = j0; j < j0 + JCHUNK; ++j) {
        float jx = sf[j][0], jy = sf[j][1], jz = sf[j][2];  // broadcast reads
        // shift = -round(d0) in {-1,0,1}; v written as (dst+shift)-src to
        // bit-match reference's (f + SHIFT) - f rounding order.
        float sx = -rintf(jx - fx);
        float sy = -rintf(jy - fy);
        float sz = -rintf(jz - fz);
        float vx = (jx + sx) - fx;
        float vy = (jy + sy) - fy;
        float vz = (jz + sz) - fz;
        float d2 = vx*vx + vy*vy + vz*vz;
        if (sqrtf(d2) <= 0.4f) {
            a0 += vx*vx; a1 += vy*vy; a2 += vz*vz;
        }
    }

    // wave64 butterfly reduce
    for (int off = 32; off >= 1; off >>= 1) {
        a0 += __shfl_xor(a0, off);
        a1 += __shfl_xor(a1, off);
        a2 += __shfl_xor(a2, off);
    }
    __shared__ float part[4][3];
    const int wave = i >> 6;
    if ((i & 63) == 0) { part[wave][0] = a0; part[wave][1] = a1; part[wave][2] = a2; }
    __syncthreads();
    if (i == 0) {
        float* dst = sums + (size_t)blk * 3;
        dst[0] = part[0][0] + part[1][0] + part[2][0] + part[3][0];
        dst[1] = part[0][1] + part[1][1] + part[2][1] + part[3][1];
        dst[2] = part[0][2] + part[1][2] + part[2][2] + part[3][2];
    }
}

__global__ __launch_bounds__(256) void finish_kernel(
    const float* __restrict__ sums, float* __restrict__ out)
{
    const int t = threadIdx.x;        // 0..255 -> (b,k)
    const int b = t >> 4, k = t & 15;
    const float* s0p = sums + (size_t)((b * TASKS_PER_B + 0)     * JSPLIT) * 3;
    const float* skp = sums + (size_t)((b * TASKS_PER_B + 1 + k) * JSPLIT) * 3;
    float s0x = 0.f, s0y = 0.f, s0z = 0.f;
    float skx = 0.f, sky = 0.f, skz = 0.f;
    #pragma unroll
    for (int qq = 0; qq < JSPLIT; ++qq) {
        s0x += s0p[qq*3+0]; s0y += s0p[qq*3+1]; s0z += s0p[qq*3+2];
        skx += skp[qq*3+0]; sky += skp[qq*3+1]; skz += skp[qq*3+2];
    }
    float d0 = skx - s0x, d1 = sky - s0y, d2 = skz - s0z;
    float v = sqrtf(d0*d0 + d1*d1 + d2*d2);

    for (int off = 32; off >= 1; off >>= 1) v += __shfl_xor(v, off);
    __shared__ float part[4];
    if ((t & 63) == 0) part[t >> 6] = v;
    __syncthreads();
    if (t == 0) out[0] = (part[0] + part[1] + part[2] + part[3]) * (1.0f / 256.0f);
}

extern "C" void kernel_launch(void* const* d_in, const int* in_sizes, int n_in,
                              void* d_out, int out_size, void* d_ws, size_t ws_size,
                              hipStream_t stream) {
    const float* fracs = (const float*)d_in[0];
    const float* oprss = (const float*)d_in[2];
    float* out  = (float*)d_out;
    float* sums = (float*)d_ws;      // NB*17*JSPLIT*3 floats = 13 KB

    const int nblk = NB * TASKS_PER_B * JSPLIT;   // 1088
    pair_kernel<<<nblk, 256, 0, stream>>>(fracs, oprss, sums);
    finish_kernel<<<1, 256, 0, stream>>>(sums, out);
}

// Round 2
// 14.727 us; speedup vs baseline: 1.9304x; 1.9304x over previous
//
#include <hip/hip_runtime.h>
#include <math.h>

// SGO_Loss_Prod: B=16 structures, N=256 atoms, K=16 ops, r=0.4.
// Min-image collapse: r=0.4 < 0.5 so at most one of the 27 periodic shifts
// passes the mask per pair -> compute minimum image directly (validated
// bit-exact in R1, absmax 0.0).
// R2: rotational half-shell — thread i visits j=(i+t)&255, t=1..128 only;
// each unordered pair counted once at weight 2 (t=128 at weight 1: both
// endpoints visit it). Mask via d2 <= r^2 (sqrt is monotone).

#define NATOMS 256
#define KOPS   16
#define NB     16
#define TASKS_PER_B (KOPS + 1)   // identity + 16 ops
#define JSPLIT 4                 // t-range 1..128 split 4 ways
#define TCHUNK 32

// Replicates jnp.mod(x, 1.0) (validated bit-exact in R1).
__device__ __forceinline__ float wrap01(float x) {
    float m = fmodf(x, 1.0f);
    if (m < 0.0f) m += 1.0f;
    return m;
}

__global__ __launch_bounds__(256) void pair_kernel(
    const float* __restrict__ fracs,
    const float* __restrict__ oprss,
    float* __restrict__ sums)        // [NB*17*JSPLIT][3]
{
    const int blk  = blockIdx.x;      // 0..1087
    const int task = blk >> 2;        // 0..271
    const int q    = blk & 3;         // t-chunk
    const int b    = task / TASKS_PER_B;
    const int t    = task - b * TASKS_PER_B;   // 0 = identity, 1..16 = op t-1

    const int i = threadIdx.x;        // src atom
    const float* f = fracs + (size_t)b * NATOMS * 3;

    __shared__ float4 sf[NATOMS];

    float fx = f[i*3+0], fy = f[i*3+1], fz = f[i*3+2];
    if (t > 0) {
        const float* op = oprss + (size_t)(b * KOPS + (t - 1)) * 9;
        // f1[i] = f[i] @ opr.T ; component c = dot(opr row c, f[i]); then mod 1
        float gx = wrap01(fx*op[0] + fy*op[1] + fz*op[2]);
        float gy = wrap01(fx*op[3] + fy*op[4] + fz*op[5]);
        float gz = wrap01(fx*op[6] + fy*op[7] + fz*op[8]);
        fx = gx; fy = gy; fz = gz;
    }
    sf[i] = make_float4(fx, fy, fz, 0.0f);
    __syncthreads();

    // weight-2 accumulation over t = tbase .. tbase+31
    float a0 = 0.f, a1 = 0.f, a2 = 0.f;
    const int tbase = q * TCHUNK + 1;
    #pragma unroll 8
    for (int u = 0; u < TCHUNK; ++u) {
        const int j = (i + tbase + u) & (NATOMS - 1);
        const float4 fj = sf[j];                 // one ds_read_b128, 16B aligned
        float dx = fj.x - fx, dy = fj.y - fy, dz = fj.z - fz;
        // (dst + shift) - src ordering matches reference rounding
        float vx = (fj.x - rintf(dx)) - fx;
        float vy = (fj.y - rintf(dy)) - fy;
        float vz = (fj.z - rintf(dz)) - fz;
        float px = vx*vx, py = vy*vy, pz = vz*vz;
        float d2 = px + py + pz;
        float m = (d2 <= 0.4f*0.4f) ? 1.0f : 0.0f;
        a0 = fmaf(px, m, a0);
        a1 = fmaf(py, m, a1);
        a2 = fmaf(pz, m, a2);
    }
    a0 *= 2.0f; a1 *= 2.0f; a2 *= 2.0f;

    // t = 128 (q==3 last iter) was counted at weight 2; net weight must be 1.
    if (q == 3) {
        const int j = (i + 128) & (NATOMS - 1);
        const float4 fj = sf[j];
        float dx = fj.x - fx, dy = fj.y - fy, dz = fj.z - fz;
        float vx = (fj.x - rintf(dx)) - fx;
        float vy = (fj.y - rintf(dy)) - fy;
        float vz = (fj.z - rintf(dz)) - fz;
        float px = vx*vx, py = vy*vy, pz = vz*vz;
        float d2 = px + py + pz;
        float m = (d2 <= 0.4f*0.4f) ? 1.0f : 0.0f;
        a0 = fmaf(px, -m, a0);
        a1 = fmaf(py, -m, a1);
        a2 = fmaf(pz, -m, a2);
    }

    // wave64 butterfly reduce
    for (int off = 32; off >= 1; off >>= 1) {
        a0 += __shfl_xor(a0, off);
        a1 += __shfl_xor(a1, off);
        a2 += __shfl_xor(a2, off);
    }
    __shared__ float part[4][3];
    const int wave = i >> 6;
    if ((i & 63) == 0) { part[wave][0] = a0; part[wave][1] = a1; part[wave][2] = a2; }
    __syncthreads();
    if (i == 0) {
        float* dst = sums + (size_t)blk * 3;
        dst[0] = part[0][0] + part[1][0] + part[2][0] + part[3][0];
        dst[1] = part[0][1] + part[1][1] + part[2][1] + part[3][1];
        dst[2] = part[0][2] + part[1][2] + part[2][2] + part[3][2];
    }
}

__global__ __launch_bounds__(256) void finish_kernel(
    const float* __restrict__ sums, float* __restrict__ out)
{
    const int t = threadIdx.x;        // 0..255 -> (b,k)
    const int b = t >> 4, k = t & 15;
    const float* s0p = sums + (size_t)((b * TASKS_PER_B + 0)     * JSPLIT) * 3;
    const float* skp = sums + (size_t)((b * TASKS_PER_B + 1 + k) * JSPLIT) * 3;
    float s0x = 0.f, s0y = 0.f, s0z = 0.f;
    float skx = 0.f, sky = 0.f, skz = 0.f;
    #pragma unroll
    for (int qq = 0; qq < JSPLIT; ++qq) {
        s0x += s0p[qq*3+0]; s0y += s0p[qq*3+1]; s0z += s0p[qq*3+2];
        skx += skp[qq*3+0]; sky += skp[qq*3+1]; skz += skp[qq*3+2];
    }
    float d0 = skx - s0x, d1 = sky - s0y, d2 = skz - s0z;
    float v = sqrtf(d0*d0 + d1*d1 + d2*d2);

    for (int off = 32; off >= 1; off >>= 1) v += __shfl_xor(v, off);
    __shared__ float part[4];
    if ((t & 63) == 0) part[t >> 6] = v;
    __syncthreads();
    if (t == 0) out[0] = (part[0] + part[1] + part[2] + part[3]) * (1.0f / 256.0f);
}

extern "C" void kernel_launch(void* const* d_in, const int* in_sizes, int n_in,
                              void* d_out, int out_size, void* d_ws, size_t ws_size,
                              hipStream_t stream) {
    const float* fracs = (const float*)d_in[0];
    const float* oprss = (const float*)d_in[2];
    float* out  = (float*)d_out;
    float* sums = (float*)d_ws;      // NB*17*JSPLIT*3 floats ≈ 13 KB

    const int nblk = NB * TASKS_PER_B * JSPLIT;   // 1088
    pair_kernel<<<nblk, 256, 0, stream>>>(fracs, oprss, sums);
    finish_kernel<<<1, 256, 0, stream>>>(sums, out);
}